// Round 2
// baseline (361.903 us; speedup 1.0000x reference)
//
#include <hip/hip_runtime.h>

// SudokuLoss dense rewrite: B=65536 puzzles, G=9, C=10.
// Thread = one puzzle ROW (9 cells, 360 B contiguous logits).
// Wave = 7 puzzles (63 lanes, lane 63 idle). Block = 256 thr = 28 puzzles.
// - row sums / box partials: registers (static indexing)
// - boxes: shfl_down over the 3 consecutive row-lanes
// - columns: LDS ds_add_f32, guarded by mask (~10% lanes -> ~no conflicts)
// - per-block partials written to distinct ws slots (no memset, no global atomics)

constexpr int kB = 65536;
constexpr int kPuzzPerWave  = 7;
constexpr int kWavesPerBlk  = 4;
constexpr int kPuzzPerBlk   = kPuzzPerWave * kWavesPerBlk;          // 28
constexpr int kBlocks       = (kB + kPuzzPerBlk - 1) / kPuzzPerBlk; // 2341

__global__ __launch_bounds__(256) void sudoku_main(
    const float* __restrict__ logits,
    const int*   __restrict__ targets,
    const int*   __restrict__ puzzles,
    float*       __restrict__ ws)  // [0,kBlocks): diff2, [kBlocks,2k): ce, [2k,3k): mcnt
{
    // colacc: per local puzzle, 9 cols x (slot0=count, slot1..9=classes)
    __shared__ float colacc[kPuzzPerBlk * 90];
    __shared__ float red[kWavesPerBlk][3];

    const int tid = threadIdx.x;
    #pragma unroll
    for (int i = tid; i < kPuzzPerBlk * 90; i += 256) colacc[i] = 0.f;
    __syncthreads();

    const int wave = tid >> 6;
    const int lane = tid & 63;
    const int plw  = lane / 9;          // 0..7 (7 == idle lane 63)
    const int r    = lane - plw * 9;    // row index 0..8 (also col index in phase 2)
    const int pLoc = wave * kPuzzPerWave + plw;       // local puzzle in block
    const int p    = blockIdx.x * kPuzzPerBlk + pLoc; // global puzzle

    const bool active = (plw < kPuzzPerWave) && (p < kB);

    float ce = 0.f, rowm = 0.f, diff2 = 0.f;
    float rowsum[9];
    float boxp[3][9];     // [bj][class-1] partial over this thread's row
    float bm[3] = {0.f, 0.f, 0.f};
    #pragma unroll
    for (int c = 0; c < 9; ++c) rowsum[c] = 0.f;
    #pragma unroll
    for (int b = 0; b < 3; ++b)
        #pragma unroll
        for (int c = 0; c < 9; ++c) boxp[b][c] = 0.f;

    if (active) {
        const float* lg = logits  + (size_t)p * 810 + r * 90;
        const int*   tg = targets + (size_t)p * 81  + r * 9;
        const int*   pz = puzzles + (size_t)p * 81  + r * 9;

        int pzv[9], tgv[9];
        #pragma unroll
        for (int j = 0; j < 9; ++j) pzv[j] = pz[j];
        #pragma unroll
        for (int j = 0; j < 9; ++j) tgv[j] = tg[j];

        float* colrow = &colacc[pLoc * 90];

        #pragma unroll
        for (int j = 0; j < 9; ++j) {
            const float* xp = lg + j * 10;   // 8B-aligned always
            float x[10];
            #pragma unroll
            for (int h = 0; h < 5; ++h) {
                const float2 v = *(const float2*)(xp + 2 * h);
                x[2 * h] = v.x; x[2 * h + 1] = v.y;
            }
            float mx = x[0];
            #pragma unroll
            for (int c = 1; c < 10; ++c) mx = fmaxf(mx, x[c]);
            float e[10], S = 0.f;
            #pragma unroll
            for (int c = 0; c < 10; ++c) { e[c] = __expf(x[c] - mx); S += e[c]; }
            const float inv = 1.f / S;
            const float lse = __logf(S);

            const int t = tgv[j];
            float xt = x[0];
            #pragma unroll
            for (int c = 1; c < 10; ++c) xt = (t == c) ? x[c] : xt;

            const float maskf = (pzv[j] == 0) ? 1.f : 0.f;
            ce   += maskf * (mx + lse - xt);
            rowm += maskf;
            const int jb = j / 3;            // compile-time (j unrolled)
            bm[jb] += maskf;

            const float winv = inv * maskf;
            float w[9];
            #pragma unroll
            for (int c = 1; c < 10; ++c) {
                w[c - 1] = e[c] * winv;
                rowsum[c - 1]   += w[c - 1];
                boxp[jb][c - 1] += w[c - 1];
            }
            // column accumulation: only masked lanes touch LDS (~10%)
            if (pzv[j] == 0) {
                float* cb = colrow + j * 10;
                atomicAdd(&cb[0], 1.f);
                #pragma unroll
                for (int c = 1; c < 10; ++c) atomicAdd(&cb[c], w[c - 1]);
            }
        }

        // row MSE (local)
        const float tr = rowm * (1.f / 9.f);
        #pragma unroll
        for (int c = 0; c < 9; ++c) { const float d = rowsum[c] - tr; diff2 += d * d; }

        // box MSE: sum partials over the 3 consecutive row-lanes (r, r+1, r+2)
        const bool boxLead = (r == 0) || (r == 3) || (r == 6);
        #pragma unroll
        for (int bj = 0; bj < 3; ++bj) {
            float bmm = bm[bj];
            bmm += __shfl_down(bm[bj], 1);
            bmm += __shfl_down(bm[bj], 2);
            const float tb = bmm * (1.f / 9.f);
            #pragma unroll
            for (int c = 0; c < 9; ++c) {
                float bs = boxp[bj][c];
                bs += __shfl_down(boxp[bj][c], 1);
                bs += __shfl_down(boxp[bj][c], 2);
                const float d = bs - tb;
                diff2 += boxLead ? d * d : 0.f;
            }
        }
    }

    __syncthreads();

    // column MSE: lane (plw, r) handles column j=r of local puzzle pLoc
    if (active) {
        const float* cb = &colacc[pLoc * 90 + r * 10];
        const float tc = cb[0] * (1.f / 9.f);
        #pragma unroll
        for (int c = 1; c < 10; ++c) { const float d = cb[c] - tc; diff2 += d * d; }
    }

    // wave reduction (inactive lanes carry zeros)
    #pragma unroll
    for (int off = 32; off > 0; off >>= 1) {
        diff2 += __shfl_down(diff2, off);
        ce    += __shfl_down(ce, off);
        rowm  += __shfl_down(rowm, off);
    }
    if (lane == 0) { red[wave][0] = diff2; red[wave][1] = ce; red[wave][2] = rowm; }
    __syncthreads();
    if (tid == 0) {
        float d = 0.f, c2 = 0.f, m = 0.f;
        #pragma unroll
        for (int wv = 0; wv < kWavesPerBlk; ++wv) {
            d += red[wv][0]; c2 += red[wv][1]; m += red[wv][2];
        }
        const int b = blockIdx.x;
        ws[b]               = d;
        ws[kBlocks + b]     = c2;
        ws[2 * kBlocks + b] = m;
    }
}

__global__ __launch_bounds__(256) void sudoku_final(
    const float* __restrict__ ws, float* __restrict__ out)
{
    __shared__ float red[4][3];
    float s0 = 0.f, s1 = 0.f, s2 = 0.f;
    for (int i = threadIdx.x; i < kBlocks; i += 256) {
        s0 += ws[i];
        s1 += ws[kBlocks + i];
        s2 += ws[2 * kBlocks + i];
    }
    #pragma unroll
    for (int off = 32; off > 0; off >>= 1) {
        s0 += __shfl_down(s0, off);
        s1 += __shfl_down(s1, off);
        s2 += __shfl_down(s2, off);
    }
    const int wave = threadIdx.x >> 6;
    if ((threadIdx.x & 63) == 0) { red[wave][0] = s0; red[wave][1] = s1; red[wave][2] = s2; }
    __syncthreads();
    if (threadIdx.x == 0) {
        float d = 0.f, c2 = 0.f, m = 0.f;
        #pragma unroll
        for (int wv = 0; wv < 4; ++wv) { d += red[wv][0]; c2 += red[wv][1]; m += red[wv][2]; }
        const float ce_loss    = c2 / (m + 1e-8f);
        const float constraint = d / ((float)kB * 9.f * 27.f);
        out[0] = ce_loss + 0.1f * constraint;
        out[1] = ce_loss;
        out[2] = constraint;
    }
}

extern "C" void kernel_launch(void* const* d_in, const int* in_sizes, int n_in,
                              void* d_out, int out_size, void* d_ws, size_t ws_size,
                              hipStream_t stream)
{
    const float* logits  = (const float*)d_in[0];
    const int*   targets = (const int*)d_in[1];
    const int*   puzzles = (const int*)d_in[2];
    float* ws  = (float*)d_ws;
    float* out = (float*)d_out;

    sudoku_main<<<kBlocks, 256, 0, stream>>>(logits, targets, puzzles, ws);
    sudoku_final<<<1, 256, 0, stream>>>(ws, out);
}